// Round 6
// baseline (324.904 us; speedup 1.0000x reference)
//
#include <hip/hip_runtime.h>
#include <hip/hip_bf16.h>

#define BB  64
#define JJ  2048
#define DI  16
#define KC  32
#define DOO 32
#define NKO 1024   // KC*DOO

typedef __bf16 bf16;
typedef __attribute__((ext_vector_type(8))) __bf16 bf16x8;
typedef __attribute__((ext_vector_type(4))) __bf16 bf16x4;
typedef __attribute__((ext_vector_type(4))) float f32x4;

// ---------------- prep: W f32 [J][K][Di][Do] -> bf16 MFMA fragment layout ----------------
// Coalesced float4 reads -> LDS (pad-33 transpose) -> packed bf16x8 fragment stores.
// Fragment layout: elem = j*16384 + t*256 + h2*128 + col*8 + e  holds
//   W[j][ko>>5][i = h2*8 + e][ko&31],  ko = t*16 + col.
// Used as A-operand (row=ko, k=i) OR B-operand (col=ko, k=i) — lane maps are symmetric.
__global__ __launch_bounds__(256)
void prep_w2(const float* __restrict__ W, bf16* __restrict__ Wfrag)
{
    __shared__ float wl[8 * 528];   // 8 k-loc x (16 i x 33 pad)
    const int tid = threadIdx.x;
    const int j = blockIdx.x;
    const float* Wj = W + (size_t)j * 16384;
    bf16* Fj = Wfrag + (size_t)j * 16384;

    for (int kg = 0; kg < 4; ++kg) {
#pragma unroll
        for (int it = 0; it < 4; ++it) {
            int q = it * 256 + tid;                 // float4 index < 1024
            float4 v4 = *reinterpret_cast<const float4*>(Wj + (size_t)kg * 4096 + (size_t)q * 4);
            int flat = q * 4;
            int kl = flat >> 9, rem = flat & 511;
            int i = rem >> 5, o = rem & 31;
            float* d = wl + kl * 528 + i * 33 + o;
            d[0] = v4.x; d[1] = v4.y; d[2] = v4.z; d[3] = v4.w;
        }
        __syncthreads();
#pragma unroll
        for (int it = 0; it < 2; ++it) {
            int q = it * 256 + tid;                 // chunk < 512
            int col = q & 15, h2 = (q >> 4) & 1, p = (q >> 5) & 1, kl = q >> 6;
            int t = (kg * 8 + kl) * 2 + p;
            int o = p * 16 + col;
            bf16x8 o8;
#pragma unroll
            for (int e = 0; e < 8; ++e)
                o8[e] = (bf16)wl[kl * 528 + (h2 * 8 + e) * 33 + o];
            *reinterpret_cast<bf16x8*>(Fj + t * 256 + h2 * 128 + col * 8) = o8;
        }
        __syncthreads();
    }
}

// ---------------- prep: X f32 [B][J][Di] -> bf16 fragment layout ----------------
// Xfrag[((j*4 + c)*32 + l)*8 + e] = X[b = c*16 + (l&15)][j][i = (l>>4)*8 + e]
__global__ __launch_bounds__(256)
void prep_x(const float* __restrict__ X, bf16* __restrict__ Xfrag)
{
    int flat = blockIdx.x * 256 + threadIdx.x;        // < 262144
    int l = flat & 31;
    int c = (flat >> 5) & 3;
    int j = flat >> 7;
    int b = c * 16 + (l & 15);
    int i0 = (l >> 4) * 8;
    const float* src = X + ((size_t)b * JJ + j) * DI + i0;
    bf16x8 o8;
#pragma unroll
    for (int e = 0; e < 8; ++e) o8[e] = (bf16)src[e];
    *reinterpret_cast<bf16x8*>(Xfrag + (size_t)flat * 8) = o8;
}

// XCD-aware block decode: the 4 chunk-blocks of one j-range share an XCD L2.
__device__ __forceinline__ void decode_blk(int id, int useXcd, int& c, int& jr)
{
    if (useXcd) { c = (id >> 3) & 3; jr = ((id >> 5) << 3) | (id & 7); }
    else        { c = id & 3;        jr = id >> 2; }
}

// ============ SWAPPED-OPERAND SCHEME ============
// acc[t2] = mfma(A = W tile, B = X chunk): C[row = ko_sub, col = b_local].
// Lane (g = lane>>4, c0 = lane&15): b = chunk*16 + c0, ko = tile*16 + g*4 + r.
// Wave w owns tiles w*4+t2 -> k = w*2 + (t2>>1), o = (t2&1)*16 + g*4 + r.
// => v-dot is LANE-LOCAL over o (16 FMA) + 2 shfl_xor (over g). No 8-deep fold.

// ---------------- routing iteration 0 (uniform c = 1/32) ----------------
template<int UF>
__global__ __launch_bounds__(1024, 8)
void caps_init5(const bf16* __restrict__ Xfrag, const bf16* __restrict__ Wfrag,
                const float* __restrict__ Xf, const float* __restrict__ Wf,
                bf16* __restrict__ partial, int Jc)
{
    const int tid  = threadIdx.x;
    const int w    = tid >> 6;
    const int lane = tid & 63;
    const int l5   = lane & 31;
    const bool hi  = lane >= 32;
    int c, jr; decode_blk(blockIdx.x, UF, c, jr);

    const f32x4 ZV = {};
    const bf16x8 ZB = {};
    f32x4 acc[4] = {ZV, ZV, ZV, ZV};

    const int j0 = jr * Jc;
    int jend = j0 + Jc; if (jend > JJ) jend = JJ;

    int j = j0;
    if constexpr (UF) {
        for (; j + 1 < jend; j += 2) {            // lanes>=32 carry j+1 (K rows 16..31)
            const int js = j + (hi ? 1 : 0);
            bf16x8 fx = *reinterpret_cast<const bf16x8*>(
                Xfrag + (((size_t)js * 4 + c) * 32 + l5) * 8);
#pragma unroll
            for (int t2 = 0; t2 < 4; ++t2) {
                bf16x8 fw = *reinterpret_cast<const bf16x8*>(
                    Wfrag + (((size_t)js * 64 + w * 4 + t2) * 32 + l5) * 8);
                acc[t2] = __builtin_amdgcn_mfma_f32_16x16x32_bf16(fw, fx, acc[t2], 0, 0, 0);
            }
        }
    }
    for (; j < jend; ++j) {    // tail / raw-f32 fallback (K rows 16..31 zero)
        bf16x8 fx = ZB;
        if (!hi) {
            if constexpr (UF) {
                fx = *reinterpret_cast<const bf16x8*>(Xfrag + (((size_t)j * 4 + c) * 32 + l5) * 8);
            } else {
                const float* s = Xf + ((size_t)(c * 16 + (l5 & 15)) * JJ + j) * DI + (l5 >> 4) * 8;
#pragma unroll
                for (int e = 0; e < 8; ++e) fx[e] = (bf16)s[e];
            }
        }
#pragma unroll
        for (int t2 = 0; t2 < 4; ++t2) {
            bf16x8 fw = ZB;
            if (!hi) {
                if constexpr (UF) {
                    fw = *reinterpret_cast<const bf16x8*>(
                        Wfrag + (((size_t)j * 64 + w * 4 + t2) * 32 + l5) * 8);
                } else {
                    int ko = (w * 4 + t2) * 16 + (l5 & 15);
                    const float* s = Wf + (size_t)j * 16384 + (size_t)(ko >> 5) * 512
                                   + (size_t)((l5 >> 4) * 8) * 32 + (ko & 31);
#pragma unroll
                    for (int e = 0; e < 8; ++e) fw[e] = (bf16)s[e * 32];
                }
            }
            acc[t2] = __builtin_amdgcn_mfma_f32_16x16x32_bf16(fw, fx, acc[t2], 0, 0, 0);
        }
    }

    // partial[jr] elem ((c*64 + tile)*64 + lane)*4 + r  <->  (b = c*16+c0, ko = tile*16+g*4+r)
    bf16* pout = partial + (size_t)jr * (BB * NKO);
#pragma unroll
    for (int t2 = 0; t2 < 4; ++t2) {
        bf16x4 o4;
#pragma unroll
        for (int r = 0; r < 4; ++r) o4[r] = (bf16)(acc[t2][r] * 0.03125f);
        *reinterpret_cast<bf16x4*>(pout + (((size_t)c * 64 + (w * 4 + t2)) * 64 + lane) * 4) = o4;
    }
}

// ---------------- routing iteration 1/2 ----------------
// Phase A: 4 MFMA -> lane-local v-dot (16 FMA) -> 2 shfl_xor per k -> 2 LDS writes.
// Phase B: softmax over K=32 (512 threads). Phase C: 4 MFMA recompute + weighted FMA.
// Frags live across barriers; hat recomputed (keeps VGPR <= 64 for 2 blocks/CU).
template<int UF>
__global__ __launch_bounds__(1024, 8)
void caps_route5(const bf16* __restrict__ Xfrag, const bf16* __restrict__ Wfrag,
                 const float* __restrict__ Xf, const float* __restrict__ Wf,
                 const float* __restrict__ vsum, bf16* __restrict__ partial, int Jc)
{
    __shared__ float clds[2][16][33];

    const int tid  = threadIdx.x;
    const int w    = tid >> 6;
    const int lane = tid & 63;
    const int g    = lane >> 4;
    const int c0   = lane & 15;
    const int l5   = lane & 31;
    const bool lo  = lane < 32;
    int c, jr; decode_blk(blockIdx.x, UF, c, jr);

    const f32x4 ZV = {};
    const bf16x8 ZB = {};
    f32x4 sacc[4] = {ZV, ZV, ZV, ZV};

    const int j0 = jr * Jc;
    int jend = j0 + Jc; if (jend > JJ) jend = JJ;

    // hoisted j-invariant v: vreg[t2][r] = v[b = c*16+c0][k = w*2+(t2>>1)][o = (t2&1)*16+g*4+r]
    f32x4 vreg[4];
    {
        const float* vb = vsum + ((size_t)(c * 16 + c0) * KC + w * 2) * DOO + g * 4;
#pragma unroll
        for (int t2 = 0; t2 < 4; ++t2) {
            float4 v4 = *reinterpret_cast<const float4*>(vb + (t2 >> 1) * DOO + (t2 & 1) * 16);
            vreg[t2][0] = v4.x; vreg[t2][1] = v4.y; vreg[t2][2] = v4.z; vreg[t2][3] = v4.w;
        }
    }

    for (int j = j0; j < jend; ++j) {
        const int pb = j & 1;

        // ---- fragment loads (live through phase C) ----
        bf16x8 fx = ZB, fw0 = ZB, fw1 = ZB, fw2 = ZB, fw3 = ZB;
        if (lo) {
            if constexpr (UF) {
                fx  = *reinterpret_cast<const bf16x8*>(Xfrag + (((size_t)j * 4 + c) * 32 + l5) * 8);
                const bf16* wb = Wfrag + (((size_t)j * 64 + w * 4) * 32 + l5) * 8;
                fw0 = *reinterpret_cast<const bf16x8*>(wb);
                fw1 = *reinterpret_cast<const bf16x8*>(wb + 256);
                fw2 = *reinterpret_cast<const bf16x8*>(wb + 512);
                fw3 = *reinterpret_cast<const bf16x8*>(wb + 768);
            } else {
                const float* s = Xf + ((size_t)(c * 16 + (l5 & 15)) * JJ + j) * DI + (l5 >> 4) * 8;
#pragma unroll
                for (int e = 0; e < 8; ++e) fx[e] = (bf16)s[e];
#pragma unroll
                for (int t2 = 0; t2 < 4; ++t2) {
                    int ko = (w * 4 + t2) * 16 + (l5 & 15);
                    const float* ws = Wf + (size_t)j * 16384 + (size_t)(ko >> 5) * 512
                                    + (size_t)((l5 >> 4) * 8) * 32 + (ko & 31);
                    bf16x8 tmp;
#pragma unroll
                    for (int e = 0; e < 8; ++e) tmp[e] = (bf16)ws[e * 32];
                    if (t2 == 0) fw0 = tmp; else if (t2 == 1) fw1 = tmp;
                    else if (t2 == 2) fw2 = tmp; else fw3 = tmp;
                }
            }
        }

        // ---- phase A: logits ----
        float lp0, lp1;
        {
            f32x4 h0 = __builtin_amdgcn_mfma_f32_16x16x32_bf16(fw0, fx, ZV, 0, 0, 0);
            f32x4 h1 = __builtin_amdgcn_mfma_f32_16x16x32_bf16(fw1, fx, ZV, 0, 0, 0);
            f32x4 h2 = __builtin_amdgcn_mfma_f32_16x16x32_bf16(fw2, fx, ZV, 0, 0, 0);
            f32x4 h3 = __builtin_amdgcn_mfma_f32_16x16x32_bf16(fw3, fx, ZV, 0, 0, 0);
            lp0 = h0[0] * vreg[0][0]; lp1 = h2[0] * vreg[2][0];
#pragma unroll
            for (int r = 1; r < 4; ++r) { lp0 += h0[r] * vreg[0][r]; lp1 += h2[r] * vreg[2][r]; }
#pragma unroll
            for (int r = 0; r < 4; ++r) { lp0 += h1[r] * vreg[1][r]; lp1 += h3[r] * vreg[3][r]; }
        }
        lp0 += __shfl_xor(lp0, 16, 64); lp0 += __shfl_xor(lp0, 32, 64);
        lp1 += __shfl_xor(lp1, 16, 64); lp1 += __shfl_xor(lp1, 32, 64);
        if (lane < 16) {
            clds[pb][c0][w * 2]     = lp0;
            clds[pb][c0][w * 2 + 1] = lp1;
        }
        __syncthreads();

        // ---- phase B: softmax over K=32 (rows = 16 b_local, 512 threads) ----
        if (tid < 512) {
            int row = tid >> 5, k = tid & 31;
            float xv = clds[pb][row][k];
            float mx = xv;
#pragma unroll
            for (int m = 1; m < 32; m <<= 1) mx = fmaxf(mx, __shfl_xor(mx, m, 64));
            float ev = __expf(xv - mx);
            float sm = ev;
#pragma unroll
            for (int m = 1; m < 32; m <<= 1) sm += __shfl_xor(sm, m, 64);
            clds[pb][row][k] = ev / sm;
        }
        __syncthreads();

        // ---- phase C: recompute hat, weighted accumulate ----
        float cw0 = clds[pb][c0][w * 2];
        float cw1 = clds[pb][c0][w * 2 + 1];
        {
            f32x4 h0 = __builtin_amdgcn_mfma_f32_16x16x32_bf16(fw0, fx, ZV, 0, 0, 0);
            f32x4 h1 = __builtin_amdgcn_mfma_f32_16x16x32_bf16(fw1, fx, ZV, 0, 0, 0);
            f32x4 h2 = __builtin_amdgcn_mfma_f32_16x16x32_bf16(fw2, fx, ZV, 0, 0, 0);
            f32x4 h3 = __builtin_amdgcn_mfma_f32_16x16x32_bf16(fw3, fx, ZV, 0, 0, 0);
#pragma unroll
            for (int r = 0; r < 4; ++r) {
                sacc[0][r] += cw0 * h0[r];
                sacc[1][r] += cw0 * h1[r];
                sacc[2][r] += cw1 * h2[r];
                sacc[3][r] += cw1 * h3[r];
            }
        }
    }

    bf16* pout = partial + (size_t)jr * (BB * NKO);
#pragma unroll
    for (int t2 = 0; t2 < 4; ++t2) {
        bf16x4 o4;
#pragma unroll
        for (int r = 0; r < 4; ++r) o4[r] = (bf16)sacc[t2][r];
        *reinterpret_cast<bf16x4*>(pout + (((size_t)c * 64 + (w * 4 + t2)) * 64 + lane) * 4) = o4;
    }
}

// ---------------- reduce partials + squash -> v ; update vsum ----------------
// 64-lane group per (c,k): lane (g,c0) holds b=c*16+c0, o = {g*4+r} U {16+g*4+r}.
__global__ __launch_bounds__(256)
void caps_reduce5(const bf16* __restrict__ partial, float* __restrict__ vsum,
                  float* __restrict__ out, int P, int vmode, int wout)
{
    int gt   = blockIdx.x * 256 + threadIdx.x;   // < 8192
    int grp  = gt >> 6;                           // 0..127 = (c, k)
    int lane = gt & 63;
    int c = grp >> 5, k = grp & 31;
    int g = lane >> 4, c0 = lane & 15;

    const bf16* base = partial + ((size_t)(c * 64 + 2 * k) * 64 + lane) * 4;
    float a0[4] = {0.f, 0.f, 0.f, 0.f}, a1[4] = {0.f, 0.f, 0.f, 0.f};
    for (int p = 0; p < P; ++p) {
        bf16x4 v0 = *reinterpret_cast<const bf16x4*>(base + (size_t)p * 65536);
        bf16x4 v1 = *reinterpret_cast<const bf16x4*>(base + 256 + (size_t)p * 65536);
#pragma unroll
        for (int r = 0; r < 4; ++r) { a0[r] += (float)v0[r]; a1[r] += (float)v1[r]; }
    }
    float s2 = 0.f;
#pragma unroll
    for (int r = 0; r < 4; ++r) s2 += a0[r] * a0[r] + a1[r] * a1[r];
    s2 += __shfl_xor(s2, 16, 64);
    s2 += __shfl_xor(s2, 32, 64);
    float scale = s2 / (1.0f + s2) / sqrtf(s2 + 1e-7f);

    int b  = c * 16 + c0;
    int e0 = (b * KC + k) * DOO + g * 4;
    float4 w0, w1;
    w0.x = scale * a0[0]; w0.y = scale * a0[1]; w0.z = scale * a0[2]; w0.w = scale * a0[3];
    w1.x = scale * a1[0]; w1.y = scale * a1[1]; w1.z = scale * a1[2]; w1.w = scale * a1[3];
    if (vmode == 0) {
        *reinterpret_cast<float4*>(vsum + e0)      = w0;
        *reinterpret_cast<float4*>(vsum + e0 + 16) = w1;
    } else if (vmode == 1) {
        float4 o0 = *reinterpret_cast<const float4*>(vsum + e0);
        float4 o1 = *reinterpret_cast<const float4*>(vsum + e0 + 16);
        o0.x += w0.x; o0.y += w0.y; o0.z += w0.z; o0.w += w0.w;
        o1.x += w1.x; o1.y += w1.y; o1.z += w1.z; o1.w += w1.w;
        *reinterpret_cast<float4*>(vsum + e0)      = o0;
        *reinterpret_cast<float4*>(vsum + e0 + 16) = o1;
    }
    if (wout) {
        *reinterpret_cast<float4*>(out + e0)      = w0;
        *reinterpret_cast<float4*>(out + e0 + 16) = w1;
    }
}

extern "C" void kernel_launch(void* const* d_in, const int* in_sizes, int n_in,
                              void* d_out, int out_size, void* d_ws, size_t ws_size,
                              hipStream_t stream)
{
    const float* X  = (const float*)d_in[0];   // [64, 2048, 16] f32
    const float* Wg = (const float*)d_in[1];   // [2048, 32, 16, 32] f32
    float* out = (float*)d_out;                // [64, 32, 32] f32

    const size_t SLICE   = (size_t)BB * NKO;               // 65536 elements
    const size_t WFRAG_B = (size_t)JJ * 64 * 32 * 8 * 2;   // 67108864
    const size_t XFRAG_B = (size_t)JJ * 4 * 32 * 8 * 2;    // 4194304
    const size_t VS_B    = SLICE * sizeof(float);          // 262144

    int P = 64;
    int useFrag = 1;
    bf16 *Wfrag = nullptr, *Xfrag = nullptr, *partial = nullptr;
    float* vsum = nullptr;

    if (ws_size >= WFRAG_B + XFRAG_B + VS_B + (size_t)P * SLICE * 2) {
        Wfrag   = (bf16*)d_ws;
        Xfrag   = (bf16*)((char*)d_ws + WFRAG_B);
        vsum    = (float*)((char*)d_ws + WFRAG_B + XFRAG_B);
        partial = (bf16*)((char*)d_ws + WFRAG_B + XFRAG_B + VS_B);
    } else {
        useFrag = 0;
        size_t avail = (ws_size > VS_B) ? (ws_size - VS_B) / (SLICE * 2) : 1;
        P = (int)avail; if (P < 1) P = 1; if (P > 64) P = 64;
        vsum    = (float*)d_ws;
        partial = (bf16*)((char*)d_ws + VS_B);
    }
    const int Jc = (JJ + P - 1) / P;

    if (useFrag) {
        prep_w2<<<dim3(2048), dim3(256), 0, stream>>>(Wg, Wfrag);
        prep_x<<<dim3(1024),  dim3(256), 0, stream>>>(X,  Xfrag);
        caps_init5<1><<<dim3(4 * P), dim3(1024), 0, stream>>>(Xfrag, Wfrag, X, Wg, partial, Jc);
        caps_reduce5<<<dim3(32), dim3(256), 0, stream>>>(partial, vsum, out, P, 0, 0);
        caps_route5<1><<<dim3(4 * P), dim3(1024), 0, stream>>>(Xfrag, Wfrag, X, Wg, vsum, partial, Jc);
        caps_reduce5<<<dim3(32), dim3(256), 0, stream>>>(partial, vsum, out, P, 1, 0);
        caps_route5<1><<<dim3(4 * P), dim3(1024), 0, stream>>>(Xfrag, Wfrag, X, Wg, vsum, partial, Jc);
        caps_reduce5<<<dim3(32), dim3(256), 0, stream>>>(partial, vsum, out, P, 2, 1);
    } else {
        caps_init5<0><<<dim3(4 * P), dim3(1024), 0, stream>>>(Xfrag, Wfrag, X, Wg, partial, Jc);
        caps_reduce5<<<dim3(32), dim3(256), 0, stream>>>(partial, vsum, out, P, 0, 0);
        caps_route5<0><<<dim3(4 * P), dim3(1024), 0, stream>>>(Xfrag, Wfrag, X, Wg, vsum, partial, Jc);
        caps_reduce5<<<dim3(32), dim3(256), 0, stream>>>(partial, vsum, out, P, 1, 0);
        caps_route5<0><<<dim3(4 * P), dim3(1024), 0, stream>>>(Xfrag, Wfrag, X, Wg, vsum, partial, Jc);
        caps_reduce5<<<dim3(32), dim3(256), 0, stream>>>(partial, vsum, out, P, 2, 1);
    }
}